// Round 1
// baseline (94.235 us; speedup 1.0000x reference)
//
#include <hip/hip_runtime.h>

#define MAX_RIGID 8
#define MAX_TORSION 7
#define MAX_ATOM 24

__device__ __forceinline__ void load12(const float* __restrict__ base, float* X) {
    const float4* p = reinterpret_cast<const float4*>(base);
    float4 a = p[0], b = p[1], c = p[2];
    X[0]=a.x; X[1]=a.y; X[2]=a.z;  X[3]=a.w;
    X[4]=b.x; X[5]=b.y; X[6]=b.z;  X[7]=b.w;
    X[8]=c.x; X[9]=c.y; X[10]=c.z; X[11]=c.w;
}

// X,Y,O are 4x3 affine: [0..8] = rot row-major, [9..11] = translation row
__device__ __forceinline__ void combine12(const float* X, const float* Y, float* O) {
    #pragma unroll
    for (int i = 0; i < 3; ++i) {
        #pragma unroll
        for (int k = 0; k < 3; ++k) {
            O[i*3+k] = X[i*3+0]*Y[0+k] + X[i*3+1]*Y[3+k] + X[i*3+2]*Y[6+k];
        }
        O[9+i] = X[i*3+0]*Y[9] + X[i*3+1]*Y[10] + X[i*3+2]*Y[11] + X[9+i];
    }
}

__global__ __launch_bounds__(256) void build_struct_kernel(
    const float* __restrict__ out0,   // [N,14]
    const float* __restrict__ out1,   // [N,3,3]
    const float* __restrict__ pos,    // [N,3]
    const float* __restrict__ rigidT, // [22,8,4,3]
    const float* __restrict__ rigidG, // [22,24,3]
    const int*   __restrict__ resty,  // [N]
    const int*   __restrict__ tdep,   // [22,8]
    const int*   __restrict__ gdep,   // [22,24]
    const int*   __restrict__ nrp,    // num_recycle (1 elem)
    float* __restrict__ dR,           // [N,24,3]
    float* __restrict__ dOprBB,       // [N,4,3]
    float* __restrict__ dBB,          // [N,4,3]
    float* __restrict__ dSC,          // [N,7,2]
    int N)
{
    int n = blockIdx.x * blockDim.x + threadIdx.x;
    if (n >= N) return;

    // robust num_recycle read (handles int32/int64/float32 encodings)
    int iv = *nrp;
    float nrv;
    if (iv > 0 && iv < 1000000) nrv = (float)iv;
    else nrv = *reinterpret_cast<const float*>(nrp);
    float tscale = 0.1f / nrv;

    // ---- sc = normalize(output_0.reshape(7,2)) ----
    const float* o0 = out0 + (size_t)n * 14;
    float sc[14];
    #pragma unroll
    for (int k = 0; k < 7; ++k) {
        float a = o0[2*k], b = o0[2*k+1];
        float r = 1.0f / sqrtf(a*a + b*b + 1e-12f);
        sc[2*k] = a*r; sc[2*k+1] = b*r;
    }

    // ---- bb: Gram-Schmidt frame + scaled translation ----
    const float* o1 = out1 + (size_t)n * 9;
    float v0x=o1[0], v0y=o1[1], v0z=o1[2];
    float v1x=o1[3], v1y=o1[4], v1z=o1[5];
    float r0 = 1.0f / sqrtf(v0x*v0x + v0y*v0y + v0z*v0z + 1e-12f);
    float e0x=v0x*r0, e0y=v0y*r0, e0z=v0z*r0;
    float dp = e0x*v1x + e0y*v1y + e0z*v1z;
    float u1x = v1x - e0x*dp, u1y = v1y - e0y*dp, u1z = v1z - e0z*dp;
    float r1 = 1.0f / sqrtf(u1x*u1x + u1y*u1y + u1z*u1z + 1e-12f);
    float e1x=u1x*r1, e1y=u1y*r1, e1z=u1z*r1;
    float e2x = e0y*e1z - e0z*e1y;
    float e2y = e0z*e1x - e0x*e1z;
    float e2z = e0x*e1y - e0y*e1x;
    float tx = tscale * o1[6], ty = tscale * o1[7], tz = tscale * o1[8];

    // bb rows: rot[r][c] = e_c[r]; row 3 = t
    float bb[12] = { e0x, e1x, e2x,
                     e0y, e1y, e2y,
                     e0z, e1z, e2z,
                     tx,  ty,  tz };

    int rt = resty[n];
    const float* Tbase = rigidT + rt * 96;
    const int*   td    = tdep   + rt * 8;
    const int*   gd    = gdep   + rt * 24;
    const float* Gb    = rigidG + rt * 72;

    float px = pos[n*3+0], py = pos[n*3+1], pz = pos[n*3+2];

    float opr[MAX_RIGID][12];

    // rigid 0: combine(T0, bb_opr) where bb_opr row3 = bb3 + pos
    {
        float X[12]; load12(Tbase, X);
        float Y[12] = { bb[0],bb[1],bb[2], bb[3],bb[4],bb[5], bb[6],bb[7],bb[8],
                        tx+px, ty+py, tz+pz };
        combine12(X, Y, opr[0]);
    }

    // rigids 1..7: M = combine(T_i, torsion_i); prev = opr[tdep[i]]; opr[i] = combine(prev, M)
    #pragma unroll
    for (int i = 1; i < MAX_RIGID; ++i) {
        float X[12]; load12(Tbase + i*12, X);
        float c = sc[2*(i-1)], s = sc[2*(i-1)+1];
        float M[12];
        M[0]=X[0]; M[3]=X[3]; M[6]=X[6];
        M[1] = c*X[1] + s*X[2];   M[2] = c*X[2] - s*X[1];
        M[4] = c*X[4] + s*X[5];   M[5] = c*X[5] - s*X[4];
        M[7] = c*X[7] + s*X[8];   M[8] = c*X[8] - s*X[7];
        M[9]=X[9]; M[10]=X[10]; M[11]=X[11];

        int t = td[i];                       // 0 <= t < i
        float P[12];
        #pragma unroll
        for (int j = 0; j < 12; ++j) P[j] = opr[0][j];
        #pragma unroll
        for (int cnd = 1; cnd < i; ++cnd) {
            bool take = (t == cnd);
            #pragma unroll
            for (int j = 0; j < 12; ++j) P[j] = take ? opr[cnd][j] : P[j];
        }
        combine12(P, M, opr[i]);
    }

    // ---- atoms: R[a] = rot(opr[gdep[a]]) @ G[a] + tr(opr[gdep[a]]) ----
    float* Rout = dR + (size_t)n * 72;
    #pragma unroll
    for (int blk = 0; blk < 6; ++blk) {
        float buf[12];
        #pragma unroll
        for (int a4 = 0; a4 < 4; ++a4) {
            int a = blk*4 + a4;
            int g = gd[a];                   // 0..7
            float O[12];
            #pragma unroll
            for (int j = 0; j < 12; ++j) O[j] = opr[0][j];
            #pragma unroll
            for (int cnd = 1; cnd < MAX_RIGID; ++cnd) {
                bool take = (g == cnd);
                #pragma unroll
                for (int j = 0; j < 12; ++j) O[j] = take ? opr[cnd][j] : O[j];
            }
            float gx = Gb[a*3+0], gy = Gb[a*3+1], gz = Gb[a*3+2];
            buf[a4*3+0] = O[0]*gx + O[1]*gy + O[2]*gz + O[9];
            buf[a4*3+1] = O[3]*gx + O[4]*gy + O[5]*gz + O[10];
            buf[a4*3+2] = O[6]*gx + O[7]*gy + O[8]*gz + O[11];
        }
        float4* dst = reinterpret_cast<float4*>(Rout + blk*12);
        dst[0] = make_float4(buf[0], buf[1], buf[2],  buf[3]);
        dst[1] = make_float4(buf[4], buf[5], buf[6],  buf[7]);
        dst[2] = make_float4(buf[8], buf[9], buf[10], buf[11]);
    }

    // ---- opr_bb (opr[0]), bb, sc outputs ----
    {
        float4* d = reinterpret_cast<float4*>(dOprBB + (size_t)n * 12);
        d[0] = make_float4(opr[0][0], opr[0][1], opr[0][2],  opr[0][3]);
        d[1] = make_float4(opr[0][4], opr[0][5], opr[0][6],  opr[0][7]);
        d[2] = make_float4(opr[0][8], opr[0][9], opr[0][10], opr[0][11]);
    }
    {
        float4* d = reinterpret_cast<float4*>(dBB + (size_t)n * 12);
        d[0] = make_float4(bb[0], bb[1], bb[2],  bb[3]);
        d[1] = make_float4(bb[4], bb[5], bb[6],  bb[7]);
        d[2] = make_float4(bb[8], bb[9], bb[10], bb[11]);
    }
    {
        float2* d = reinterpret_cast<float2*>(dSC + (size_t)n * 14);
        #pragma unroll
        for (int k = 0; k < 7; ++k) d[k] = make_float2(sc[2*k], sc[2*k+1]);
    }
}

extern "C" void kernel_launch(void* const* d_in, const int* in_sizes, int n_in,
                              void* d_out, int out_size, void* d_ws, size_t ws_size,
                              hipStream_t stream) {
    const float* out0 = (const float*)d_in[0];
    const float* out1 = (const float*)d_in[1];
    const float* pos  = (const float*)d_in[2];
    const float* rT   = (const float*)d_in[3];
    const float* rG   = (const float*)d_in[4];
    const int*   res  = (const int*)d_in[5];
    const int*   td   = (const int*)d_in[6];
    const int*   gd   = (const int*)d_in[7];
    const int*   nr   = (const int*)d_in[8];

    int N = in_sizes[5];  // residue_type count = N_NODES

    float* dR     = (float*)d_out;
    float* dOprBB = dR + (size_t)N * 72;
    float* dBB   = dOprBB + (size_t)N * 12;
    float* dSC   = dBB + (size_t)N * 12;

    dim3 grid((N + 255) / 256), block(256);
    hipLaunchKernelGGL(build_struct_kernel, grid, block, 0, stream,
                       out0, out1, pos, rT, rG, res, td, gd, nr,
                       dR, dOprBB, dBB, dSC, N);
}